// Round 6
// baseline (348.214 us; speedup 1.0000x reference)
//
#include <hip/hip_runtime.h>

#define D   640
#define NB  2048
#define LQ  32

typedef float v2f __attribute__((ext_vector_type(2)));

// ---------------------------------------------------------------------------
// Kernel A: t[b,:] = (sum_d v[b,d]) * v[b,:] + k[b,:]
// One block per batch b. 160 float4 per row; threads 0..159 each own one f4.
// ---------------------------------------------------------------------------
__global__ __launch_bounds__(256) void compute_t_kernel(
    const float* __restrict__ v, const float* __restrict__ kin,
    float* __restrict__ T) {
  const int b   = blockIdx.x;
  const int tid = threadIdx.x;
  const float4* v4 = (const float4*)(v + b * D);
  const float4* k4 = (const float4*)(kin + b * D);

  float4 vv = make_float4(0.f, 0.f, 0.f, 0.f);
  if (tid < 160) vv = v4[tid];
  float s = vv.x + vv.y + vv.z + vv.w;

  #pragma unroll
  for (int off = 32; off; off >>= 1) s += __shfl_xor(s, off);

  __shared__ float red[4];
  if ((tid & 63) == 0) red[tid >> 6] = s;
  __syncthreads();
  const float tot = red[0] + red[1] + red[2] + red[3];

  if (tid < 160) {
    float4 kv = k4[tid];
    float4 t;
    t.x = tot * vv.x + kv.x;
    t.y = tot * vv.y + kv.y;
    t.z = tot * vv.z + kv.z;
    t.w = tot * vv.w + kv.w;
    ((float4*)(T + b * D))[tid] = t;
  }
}

// ---------------------------------------------------------------------------
// Kernel B: G[m,n] = (sum_k T[m,k] * W[n,k] + b_fc[n]) * gamma1[n]
// fp32 tiled GEMM. BM=32 BN=64 BK=32 -> grid 64x10 = 640 blocks (2.5/CU,
// better balance than 320). 256 threads, 2x4 micro-tile.
// ---------------------------------------------------------------------------
#define BM 32
#define BN 64
#define BK 32

__global__ __launch_bounds__(256) void gemm_tn_kernel(
    const float* __restrict__ T, const float* __restrict__ W,
    const float* __restrict__ bfc, const float* __restrict__ g1,
    float* __restrict__ G) {
  // +4 pad keeps rows 16B-multiples so float2/float4 LDS reads stay aligned.
  __shared__ __align__(16) float As[BK][BM + 4];   // 32 x 36
  __shared__ __align__(16) float Bs[BK][BN + 4];   // 32 x 68

  const int tid = threadIdx.x;
  const int bm  = blockIdx.x * BM;
  const int bn  = blockIdx.y * BN;

  // A staging: 32 rows x 8 float4 -> 1 per thread
  const int ar = tid >> 3;          // 0..31
  const int ac = (tid & 7) << 2;    // 0,4,..,28
  // B staging: 64 rows x 8 float4 -> 2 per thread
  const int br = tid >> 2;          // 0..63
  const int bc = (tid & 3) << 2;    // 0,4,8,12  (and +16)

  const int tm = (tid & 15) << 1;   // 0..30 step 2
  const int tn = (tid >> 4) << 2;   // 0..60 step 4

  const float* Arow = T + (bm + ar) * D;
  const float* Brow = W + (bn + br) * D;

  float acc[2][4] = {};

  for (int k0 = 0; k0 < D; k0 += BK) {
    float4 a  = *(const float4*)(Arow + k0 + ac);
    float4 b0 = *(const float4*)(Brow + k0 + bc);
    float4 b1 = *(const float4*)(Brow + k0 + bc + 16);
    __syncthreads();   // protect previous iteration's LDS reads
    As[ac + 0][ar] = a.x;  As[ac + 1][ar] = a.y;
    As[ac + 2][ar] = a.z;  As[ac + 3][ar] = a.w;
    Bs[bc + 0][br] = b0.x; Bs[bc + 1][br] = b0.y;
    Bs[bc + 2][br] = b0.z; Bs[bc + 3][br] = b0.w;
    Bs[bc + 16][br] = b1.x; Bs[bc + 17][br] = b1.y;
    Bs[bc + 18][br] = b1.z; Bs[bc + 19][br] = b1.w;
    __syncthreads();

    #pragma unroll
    for (int kk = 0; kk < BK; ++kk) {
      v2f    av = *(const v2f*)&As[kk][tm];
      float4 bv = *(const float4*)&Bs[kk][tn];
      acc[0][0] += av.x * bv.x; acc[0][1] += av.x * bv.y;
      acc[0][2] += av.x * bv.z; acc[0][3] += av.x * bv.w;
      acc[1][0] += av.y * bv.x; acc[1][1] += av.y * bv.y;
      acc[1][2] += av.y * bv.z; acc[1][3] += av.y * bv.w;
    }
  }

  const int n = bn + tn;
  const float4 bf = *(const float4*)(bfc + n);
  const float4 gg = *(const float4*)(g1 + n);
  #pragma unroll
  for (int i = 0; i < 2; ++i) {
    const int m = bm + tm + i;
    float4 r;
    r.x = (acc[i][0] + bf.x) * gg.x;
    r.y = (acc[i][1] + bf.y) * gg.y;
    r.z = (acc[i][2] + bf.z) * gg.z;
    r.w = (acc[i][3] + bf.w) * gg.w;
    *(float4*)(G + m * D + n) = r;
  }
}

// ---------------------------------------------------------------------------
// Kernel C: out[r,:] = LayerNorm(q[r,:] + G[r>>5,:])   (row length 640)
// One wave per row; 320 float2 per row = exactly 5 per lane (balanced).
// Nontemporal q-load / out-store keep the streaming 335 MB out of L2 so
// G / ln params stay resident.
// ---------------------------------------------------------------------------
__global__ __launch_bounds__(256) void ln_fused_kernel(
    const float* __restrict__ q, const float* __restrict__ G,
    const float* __restrict__ lw, const float* __restrict__ lb,
    float* __restrict__ out) {
  const int lane = threadIdx.x & 63;
  const int wv   = threadIdx.x >> 6;
  const int r    = blockIdx.x * 4 + wv;       // row 0..65535
  const int b    = r >> 5;                    // batch

  const v2f* q2 = (const v2f*)(q + r * D);
  const v2f* g2 = (const v2f*)(G + b * D);

  v2f z[5];
  float s = 0.f, ss = 0.f;

  #pragma unroll
  for (int i = 0; i < 5; ++i) {
    const int idx = lane + 64 * i;
    v2f a = __builtin_nontemporal_load(q2 + idx);
    v2f g = g2[idx];
    z[i] = a + g;
    s  += z[i].x + z[i].y;
    ss += z[i].x * z[i].x + z[i].y * z[i].y;
  }

  #pragma unroll
  for (int off = 32; off; off >>= 1) {
    s  += __shfl_xor(s, off);
    ss += __shfl_xor(ss, off);
  }

  const float inv_n = 1.0f / (float)D;
  const float mean  = s * inv_n;
  const float var   = ss * inv_n - mean * mean;
  const float rs    = rsqrtf(var + 1e-5f);

  v2f* o2 = (v2f*)(out + r * D);
  const v2f* w2 = (const v2f*)lw;
  const v2f* b2 = (const v2f*)lb;

  #pragma unroll
  for (int i = 0; i < 5; ++i) {
    const int idx = lane + 64 * i;
    v2f w = w2[idx];
    v2f bb = b2[idx];
    v2f o;
    o.x = (z[i].x - mean) * rs * w.x + bb.x;
    o.y = (z[i].y - mean) * rs * w.y + bb.y;
    __builtin_nontemporal_store(o, o2 + idx);
  }
}

// ---------------------------------------------------------------------------
extern "C" void kernel_launch(void* const* d_in, const int* in_sizes, int n_in,
                              void* d_out, int out_size, void* d_ws, size_t ws_size,
                              hipStream_t stream) {
  const float* q    = (const float*)d_in[0];
  const float* k    = (const float*)d_in[1];
  const float* v    = (const float*)d_in[2];
  const float* w_fc = (const float*)d_in[3];
  const float* b_fc = (const float*)d_in[4];
  const float* g1   = (const float*)d_in[5];
  const float* lw   = (const float*)d_in[6];
  const float* lb   = (const float*)d_in[7];
  float* out = (float*)d_out;

  float* T = (float*)d_ws;            // 2048*640 floats = 5.24 MB
  float* G = T + NB * D;              // 2048*640 floats = 5.24 MB

  compute_t_kernel<<<NB, 256, 0, stream>>>(v, k, T);

  dim3 g2(NB / BM, D / BN);           // 64 x 10 = 640 blocks
  gemm_tn_kernel<<<g2, 256, 0, stream>>>(T, w_fc, b_fc, g1, G);

  const int rows = NB * LQ;           // 65536
  ln_fused_kernel<<<rows / 4, 256, 0, stream>>>(q, G, lw, lb, out);
}

// Round 10
// 343.579 us; speedup vs baseline: 1.0135x; 1.0135x over previous
//
#include <hip/hip_runtime.h>

#define D   640
#define NB  2048
#define LQ  32

typedef float v2f __attribute__((ext_vector_type(2)));

// ---------------------------------------------------------------------------
// Kernel A: t[b,:] = (sum_d v[b,d]) * v[b,:] + k[b,:]
// Wave-per-batch: 512 blocks x 256 thr; each wave owns one batch row.
// 320 float2 per row = exactly 5 per lane. No LDS, no __syncthreads.
// ---------------------------------------------------------------------------
__global__ __launch_bounds__(256) void compute_t_kernel(
    const float* __restrict__ v, const float* __restrict__ kin,
    float* __restrict__ T) {
  const int lane = threadIdx.x & 63;
  const int wv   = threadIdx.x >> 6;
  const int b    = blockIdx.x * 4 + wv;

  const v2f* v2 = (const v2f*)(v + b * D);
  const v2f* k2 = (const v2f*)(kin + b * D);

  v2f vv[5];
  float s = 0.f;
  #pragma unroll
  for (int i = 0; i < 5; ++i) {
    vv[i] = v2[lane + 64 * i];
    s += vv[i].x + vv[i].y;
  }

  #pragma unroll
  for (int off = 32; off; off >>= 1) s += __shfl_xor(s, off);

  v2f* t2 = (v2f*)(T + b * D);
  #pragma unroll
  for (int i = 0; i < 5; ++i) {
    const int idx = lane + 64 * i;
    v2f kk = k2[idx];
    v2f t;
    t.x = s * vv[i].x + kk.x;
    t.y = s * vv[i].y + kk.y;
    t2[idx] = t;
  }
}

// ---------------------------------------------------------------------------
// Kernel B: G[m,n] = (sum_k T[m,k] * W[n,k] + b_fc[n]) * gamma1[n]
// fp32 GEMM, BM=32 BN=64 BK=32, 128 threads, 4x4 micro-tile.
// Grid 64x10 = 640 blocks (2.5/CU). 16 FMA per 2 ds_read_b128 (0.125
// reads/FMA, 2x better than previous 2x4) -> VALU-bound at ~75-80%.
// ---------------------------------------------------------------------------
#define BM 32
#define BN 64
#define BK 32

__global__ __launch_bounds__(128) void gemm_tn_kernel(
    const float* __restrict__ T, const float* __restrict__ W,
    const float* __restrict__ bfc, const float* __restrict__ g1,
    float* __restrict__ G) {
  // +4 pad keeps rows 16B-multiples so float4 LDS reads stay aligned.
  __shared__ __align__(16) float As[BK][BM + 4];   // 32 x 36
  __shared__ __align__(16) float Bs[BK][BN + 4];   // 32 x 68

  const int tid = threadIdx.x;
  const int bm  = blockIdx.x * BM;
  const int bn  = blockIdx.y * BN;

  // A staging: 32 rows x 8 float4, 2 per thread (cols ac, ac+16)
  const int ar = tid >> 2;          // 0..31
  const int ac = (tid & 3) << 2;    // 0,4,8,12
  // B staging: 64 rows x 8 float4, 4 per thread (cols bc,+8,+16,+24)
  const int br = tid >> 1;          // 0..63
  const int bc = (tid & 1) << 2;    // 0,4

  // compute mapping: 4x4 micro-tile
  const int tm = (tid & 7) << 2;    // 0..28 step 4
  const int tn = (tid >> 3) << 2;   // 0..60 step 4

  const float* Arow = T + (bm + ar) * D;
  const float* Brow = W + (bn + br) * D;

  float acc[4][4] = {};

  for (int k0 = 0; k0 < D; k0 += BK) {
    float4 a0 = *(const float4*)(Arow + k0 + ac);
    float4 a1 = *(const float4*)(Arow + k0 + ac + 16);
    float4 b0 = *(const float4*)(Brow + k0 + bc);
    float4 b1 = *(const float4*)(Brow + k0 + bc + 8);
    float4 b2 = *(const float4*)(Brow + k0 + bc + 16);
    float4 b3 = *(const float4*)(Brow + k0 + bc + 24);
    __syncthreads();   // protect previous iteration's LDS reads
    As[ac +  0][ar] = a0.x; As[ac +  1][ar] = a0.y;
    As[ac +  2][ar] = a0.z; As[ac +  3][ar] = a0.w;
    As[ac + 16][ar] = a1.x; As[ac + 17][ar] = a1.y;
    As[ac + 18][ar] = a1.z; As[ac + 19][ar] = a1.w;
    Bs[bc +  0][br] = b0.x; Bs[bc +  1][br] = b0.y;
    Bs[bc +  2][br] = b0.z; Bs[bc +  3][br] = b0.w;
    Bs[bc +  8][br] = b1.x; Bs[bc +  9][br] = b1.y;
    Bs[bc + 10][br] = b1.z; Bs[bc + 11][br] = b1.w;
    Bs[bc + 16][br] = b2.x; Bs[bc + 17][br] = b2.y;
    Bs[bc + 18][br] = b2.z; Bs[bc + 19][br] = b2.w;
    Bs[bc + 24][br] = b3.x; Bs[bc + 25][br] = b3.y;
    Bs[bc + 26][br] = b3.z; Bs[bc + 27][br] = b3.w;
    __syncthreads();

    #pragma unroll
    for (int kk = 0; kk < BK; ++kk) {
      float4 av = *(const float4*)&As[kk][tm];
      float4 bv = *(const float4*)&Bs[kk][tn];
      acc[0][0] += av.x * bv.x; acc[0][1] += av.x * bv.y;
      acc[0][2] += av.x * bv.z; acc[0][3] += av.x * bv.w;
      acc[1][0] += av.y * bv.x; acc[1][1] += av.y * bv.y;
      acc[1][2] += av.y * bv.z; acc[1][3] += av.y * bv.w;
      acc[2][0] += av.z * bv.x; acc[2][1] += av.z * bv.y;
      acc[2][2] += av.z * bv.z; acc[2][3] += av.z * bv.w;
      acc[3][0] += av.w * bv.x; acc[3][1] += av.w * bv.y;
      acc[3][2] += av.w * bv.z; acc[3][3] += av.w * bv.w;
    }
  }

  const int n = bn + tn;
  const float4 bf = *(const float4*)(bfc + n);
  const float4 gg = *(const float4*)(g1 + n);
  #pragma unroll
  for (int i = 0; i < 4; ++i) {
    const int m = bm + tm + i;
    float4 r;
    r.x = (acc[i][0] + bf.x) * gg.x;
    r.y = (acc[i][1] + bf.y) * gg.y;
    r.z = (acc[i][2] + bf.z) * gg.z;
    r.w = (acc[i][3] + bf.w) * gg.w;
    *(float4*)(G + m * D + n) = r;
  }
}

// ---------------------------------------------------------------------------
// Kernel C: out[r,:] = LayerNorm(q[r,:] + G[r>>5,:])   (row length 640)
// One wave per row; 320 float2 per row = exactly 5 per lane (balanced).
// Nontemporal q-load / out-store keep the streaming 335 MB out of L2 so
// G / ln params stay resident. At HBM roofline (~53 us floor).
// ---------------------------------------------------------------------------
__global__ __launch_bounds__(256) void ln_fused_kernel(
    const float* __restrict__ q, const float* __restrict__ G,
    const float* __restrict__ lw, const float* __restrict__ lb,
    float* __restrict__ out) {
  const int lane = threadIdx.x & 63;
  const int wv   = threadIdx.x >> 6;
  const int r    = blockIdx.x * 4 + wv;       // row 0..65535
  const int b    = r >> 5;                    // batch

  const v2f* q2 = (const v2f*)(q + r * D);
  const v2f* g2 = (const v2f*)(G + b * D);

  v2f z[5];
  float s = 0.f, ss = 0.f;

  #pragma unroll
  for (int i = 0; i < 5; ++i) {
    const int idx = lane + 64 * i;
    v2f a = __builtin_nontemporal_load(q2 + idx);
    v2f g = g2[idx];
    z[i] = a + g;
    s  += z[i].x + z[i].y;
    ss += z[i].x * z[i].x + z[i].y * z[i].y;
  }

  #pragma unroll
  for (int off = 32; off; off >>= 1) {
    s  += __shfl_xor(s, off);
    ss += __shfl_xor(ss, off);
  }

  const float inv_n = 1.0f / (float)D;
  const float mean  = s * inv_n;
  const float var   = ss * inv_n - mean * mean;
  const float rs    = rsqrtf(var + 1e-5f);

  v2f* o2 = (v2f*)(out + r * D);
  const v2f* w2 = (const v2f*)lw;
  const v2f* b2 = (const v2f*)lb;

  #pragma unroll
  for (int i = 0; i < 5; ++i) {
    const int idx = lane + 64 * i;
    v2f w = w2[idx];
    v2f bb = b2[idx];
    v2f o;
    o.x = (z[i].x - mean) * rs * w.x + bb.x;
    o.y = (z[i].y - mean) * rs * w.y + bb.y;
    __builtin_nontemporal_store(o, o2 + idx);
  }
}

// ---------------------------------------------------------------------------
extern "C" void kernel_launch(void* const* d_in, const int* in_sizes, int n_in,
                              void* d_out, int out_size, void* d_ws, size_t ws_size,
                              hipStream_t stream) {
  const float* q    = (const float*)d_in[0];
  const float* k    = (const float*)d_in[1];
  const float* v    = (const float*)d_in[2];
  const float* w_fc = (const float*)d_in[3];
  const float* b_fc = (const float*)d_in[4];
  const float* g1   = (const float*)d_in[5];
  const float* lw   = (const float*)d_in[6];
  const float* lb   = (const float*)d_in[7];
  float* out = (float*)d_out;

  float* T = (float*)d_ws;            // 2048*640 floats = 5.24 MB
  float* G = T + NB * D;              // 2048*640 floats = 5.24 MB

  compute_t_kernel<<<NB / 4, 256, 0, stream>>>(v, k, T);

  dim3 g2(NB / BM, D / BN);           // 64 x 10 = 640 blocks
  gemm_tn_kernel<<<g2, 128, 0, stream>>>(T, w_fc, b_fc, g1, G);

  const int rows = NB * LQ;           // 65536
  ln_fused_kernel<<<rows / 4, 256, 0, stream>>>(q, G, lw, lb, out);
}